// Round 5
// baseline (5307.567 us; speedup 1.0000x reference)
//
#include <hip/hip_runtime.h>

// ---------------------------------------------------------------------------
// 4-layer GRU stack (Keras reset_after), B=128, T=384, U=D=256.
//
// R5: ZERO inter-block communication. Launch-sequenced phases per
// (layer, 96-step segment):
//   xp_kernel (32 blocks): xp(t) = x_l(t) @ W_in + biases for the segment
//     (z,r f16 + ip f32), A-frags read directly from the fragment-ordered
//     h-sequence of layer l-1 (or staged from x for l=0).
//   rec_kernel (8 blocks, 1 per 16-row chunk): the whole recurrence for a
//     chunk in ONE block: 8 waves x (4 VGPR + 2 LDS) B-tiles, 48 MFMA/wave
//     per step (M=16,N=768,K=256), gates in-wave, h ping-pongs through LDS.
//     h never crosses a block inside a step. h-sequence streamed to global
//     (fragment order) for the next layer's xp phase; hprev carried across
//     segment launches in a small f32 buffer.
// Kernel-launch boundaries provide all ordering + cross-XCD coherence:
// no atomics, no flags, no spins, no memsets.
// ---------------------------------------------------------------------------

#define LAYERS 4
#define TSTEPS 384
#define SEG    96
#define NSEG   (TSTEPS / SEG)
#define WPL    (48 * 16 * 64 * 8)
#define TILE_STRIDE (16 * 64 * 8)

typedef _Float16 half8 __attribute__((ext_vector_type(8)));
typedef float    f32x4 __attribute__((ext_vector_type(4)));
typedef unsigned uint4v __attribute__((ext_vector_type(4)));
typedef unsigned long long ull;

// ws layout (bytes)
#define WP_OFF   0
#define BP_OFF   3145728                 // LAYERS*WPL*2
#define HST_OFF  3162112                 // 8 chunks x 16KB = 128KB hprev carry
#define HSEQ_OFF 3407872                 // 8 x 384 x 8KB = 25,165,824
#define XP_OFF   28573696                // 8 x 96 x 32KB = 25,165,824 (ends ~51.3MB)

#define MFMA __builtin_amdgcn_mfma_f32_16x16x32_f16

// ---------------------------------------------------------------------------
// Repack: W[l] -> [tile=48][kt=16][lane=64][8] fp16 B-fragments.
// n = tile*16 + (lane&15), k = kt*32 + (lane>>4)*8 + j; k<256 input, >=256 rec.
// Bias: [0:256]=bz_in+bz_rec, [256:512]=br_in+br_rec, [512:768]=b_in_h,
// [768:1024]=b_rec_h.
// ---------------------------------------------------------------------------
__global__ void repack_kernel(const float* __restrict__ k0, const float* __restrict__ rk0,
                              const float* __restrict__ b0, const float* __restrict__ kern,
                              const float* __restrict__ rkern, const float* __restrict__ bias,
                              _Float16* __restrict__ Wp, float* __restrict__ Bp)
{
    int idx = blockIdx.x * 256 + threadIdx.x;
    const int total_w = LAYERS * WPL;
    if (idx < total_w) {
        int l = idx / WPL;
        int r = idx - l * WPL;
        int j    = r & 7;
        int lane = (r >> 3) & 63;
        int kt   = (r >> 9) & 15;
        int tile = r >> 13;
        int n = tile * 16 + (lane & 15);
        int k = kt * 32 + (lane >> 4) * 8 + j;
        float v;
        if (l == 0) {
            v = (k < 256) ? k0[(size_t)k * 768 + n] : rk0[(size_t)(k - 256) * 768 + n];
        } else {
            const float* kk = kern  + (size_t)(l - 1) * 256 * 768;
            const float* rk = rkern + (size_t)(l - 1) * 256 * 768;
            v = (k < 256) ? kk[(size_t)k * 768 + n] : rk[(size_t)(k - 256) * 768 + n];
        }
        Wp[idx] = (_Float16)v;
    } else {
        int ib = idx - total_w;
        if (ib < LAYERS * 1024) {
            int l = ib >> 10;
            int i = ib & 1023;
            const float* bs = (l == 0) ? b0 : (bias + (size_t)(l - 1) * 2 * 768);
            float v;
            if (i < 512)      v = bs[i] + bs[768 + i];
            else if (i < 768) v = bs[512 + (i - 512)];
            else              v = bs[768 + 512 + (i - 768)];
            Bp[l * 1024 + i] = v;
        }
    }
}

// ---------------------------------------------------------------------------
// xp phase: grid 32 = 8 chunks x 4 t-groups; each block does SEG/4=24 steps.
// Wave w owns units 32w..32w+31: z,r tiles in VGPRs, ip tiles in LDS.
// xp slot (c, t): 32KB = z f16 [u][16 rows] (8KB) | r f16 (8KB) | ip f32 (16KB).
// ---------------------------------------------------------------------------
__launch_bounds__(512, 2)
__global__ void xp_kernel(const float* __restrict__ x, const _Float16* __restrict__ Wp,
                          const float* __restrict__ Bp, const _Float16* __restrict__ hseq,
                          char* __restrict__ xp, int l, int t0seg)
{
    __shared__ _Float16 Ax[2][4096];     // 16KB (l==0 staging)
    __shared__ _Float16 Bl[16][4096];    // 128KB: 2 LDS ip-tiles per wave

    const int tid = threadIdx.x, lane = tid & 63, w = tid >> 6;
    const int lo16 = lane & 15, q = lane >> 4;
    const int c = blockIdx.x & 7, tg = blockIdx.x >> 3;
    const int nt = SEG / 4;
    const int tb0 = t0seg + tg * nt;
    const int b0row = c * 16;

    half8 bz0f[8], bz1f[8], br0f[8], br1f[8];
    {
        const _Float16* wb = Wp + (size_t)l * WPL;
        const int zt0 = 2*w, zt1 = 2*w + 1, rt0 = 16 + 2*w, rt1 = 17 + 2*w;
        const int it0 = 32 + 2*w, it1 = 33 + 2*w;
#pragma unroll
        for (int kt = 0; kt < 8; ++kt) {
            const size_t o = ((size_t)kt * 64 + lane) * 8;   // input half kt 0..7
            bz0f[kt] = *(const half8*)(wb + (size_t)zt0 * TILE_STRIDE + o);
            bz1f[kt] = *(const half8*)(wb + (size_t)zt1 * TILE_STRIDE + o);
            br0f[kt] = *(const half8*)(wb + (size_t)rt0 * TILE_STRIDE + o);
            br1f[kt] = *(const half8*)(wb + (size_t)rt1 * TILE_STRIDE + o);
            *(half8*)(&Bl[w*2+0][(kt*64+lane)*8]) = *(const half8*)(wb + (size_t)it0 * TILE_STRIDE + o);
            *(half8*)(&Bl[w*2+1][(kt*64+lane)*8]) = *(const half8*)(wb + (size_t)it1 * TILE_STRIDE + o);
        }
    }
    const int u0 = 32 * w + lo16, u1 = u0 + 16;
    float bz0, bz1, br0, br1, bi0, bi1;
    {
        const float* bp = Bp + l * 1024;
        bz0 = bp[u0];       bz1 = bp[u1];
        br0 = bp[256 + u0]; br1 = bp[256 + u1];
        bi0 = bp[512 + u0]; bi1 = bp[512 + u1];
    }
    const unsigned zo0 = (unsigned)(u0 * 32 + q * 8), zo1 = (unsigned)(u1 * 32 + q * 8);
    const unsigned io0 = (unsigned)(16384 + u0 * 64 + q * 16);
    const unsigned io1 = (unsigned)(16384 + u1 * 64 + q * 16);

    if (l > 0) {
        __syncthreads();   // Bl ready
        for (int i = 0; i < nt; ++i) {
            const int t = tb0 + i;
            const _Float16* hs = hseq + ((size_t)c * TSTEPS + t) * 4096;  // fragment order
            f32x4 a0 = {bz0,bz0,bz0,bz0}, a1 = {bz1,bz1,bz1,bz1};
            f32x4 a2 = {br0,br0,br0,br0}, a3 = {br1,br1,br1,br1};
            f32x4 a4 = {bi0,bi0,bi0,bi0}, a5 = {bi1,bi1,bi1,bi1};
#pragma unroll
            for (int kt = 0; kt < 8; ++kt) {
                half8 a  = *(const half8*)(hs + (kt * 64 + lane) * 8);
                half8 b4 = *(const half8*)(&Bl[w*2+0][(kt*64+lane)*8]);
                half8 b5 = *(const half8*)(&Bl[w*2+1][(kt*64+lane)*8]);
                a0 = MFMA(a, bz0f[kt], a0, 0,0,0); a1 = MFMA(a, bz1f[kt], a1, 0,0,0);
                a2 = MFMA(a, br0f[kt], a2, 0,0,0); a3 = MFMA(a, br1f[kt], a3, 0,0,0);
                a4 = MFMA(a, b4, a4, 0,0,0);       a5 = MFMA(a, b5, a5, 0,0,0);
            }
            char* slot = xp + (size_t)(c * SEG + (t - t0seg)) * 32768;
            union { ull u; _Float16 h[4]; } p;
            p.h[0]=(_Float16)a0[0]; p.h[1]=(_Float16)a0[1]; p.h[2]=(_Float16)a0[2]; p.h[3]=(_Float16)a0[3];
            *(ull*)(slot + zo0) = p.u;
            p.h[0]=(_Float16)a1[0]; p.h[1]=(_Float16)a1[1]; p.h[2]=(_Float16)a1[2]; p.h[3]=(_Float16)a1[3];
            *(ull*)(slot + zo1) = p.u;
            p.h[0]=(_Float16)a2[0]; p.h[1]=(_Float16)a2[1]; p.h[2]=(_Float16)a2[2]; p.h[3]=(_Float16)a2[3];
            *(ull*)(slot + 8192 + zo0) = p.u;
            p.h[0]=(_Float16)a3[0]; p.h[1]=(_Float16)a3[1]; p.h[2]=(_Float16)a3[2]; p.h[3]=(_Float16)a3[3];
            *(ull*)(slot + 8192 + zo1) = p.u;
            *(f32x4*)(slot + io0) = a4;
            *(f32x4*)(slot + io1) = a5;
        }
    } else {
        const int row = tid >> 5, k8 = tid & 31;
        auto stage = [&](int t, _Float16* A) {
            const float* sp = x + ((size_t)(b0row + row) * TSTEPS + t) * 256 + k8 * 8;
            f32x4 v0 = *(const f32x4*)sp, v1 = *(const f32x4*)(sp + 4);
            half8 hh;
            hh[0]=(_Float16)v0[0]; hh[1]=(_Float16)v0[1]; hh[2]=(_Float16)v0[2]; hh[3]=(_Float16)v0[3];
            hh[4]=(_Float16)v1[0]; hh[5]=(_Float16)v1[1]; hh[6]=(_Float16)v1[2]; hh[7]=(_Float16)v1[3];
            *(half8*)(A + ((k8 >> 2) * 64 + (k8 & 3) * 16 + row) * 8) = hh;
        };
        stage(tb0, Ax[0]);
        for (int i = 0; i < nt; ++i) {
            const int t = tb0 + i;
            __syncthreads();
            if (i + 1 < nt) stage(t + 1, Ax[(i + 1) & 1]);
            const _Float16* A = Ax[i & 1];
            f32x4 a0 = {bz0,bz0,bz0,bz0}, a1 = {bz1,bz1,bz1,bz1};
            f32x4 a2 = {br0,br0,br0,br0}, a3 = {br1,br1,br1,br1};
            f32x4 a4 = {bi0,bi0,bi0,bi0}, a5 = {bi1,bi1,bi1,bi1};
#pragma unroll
            for (int kt = 0; kt < 8; ++kt) {
                half8 a  = *(const half8*)(A + (kt * 64 + lane) * 8);
                half8 b4 = *(const half8*)(&Bl[w*2+0][(kt*64+lane)*8]);
                half8 b5 = *(const half8*)(&Bl[w*2+1][(kt*64+lane)*8]);
                a0 = MFMA(a, bz0f[kt], a0, 0,0,0); a1 = MFMA(a, bz1f[kt], a1, 0,0,0);
                a2 = MFMA(a, br0f[kt], a2, 0,0,0); a3 = MFMA(a, br1f[kt], a3, 0,0,0);
                a4 = MFMA(a, b4, a4, 0,0,0);       a5 = MFMA(a, b5, a5, 0,0,0);
            }
            char* slot = xp + (size_t)(c * SEG + (t - t0seg)) * 32768;
            union { ull u; _Float16 h[4]; } p;
            p.h[0]=(_Float16)a0[0]; p.h[1]=(_Float16)a0[1]; p.h[2]=(_Float16)a0[2]; p.h[3]=(_Float16)a0[3];
            *(ull*)(slot + zo0) = p.u;
            p.h[0]=(_Float16)a1[0]; p.h[1]=(_Float16)a1[1]; p.h[2]=(_Float16)a1[2]; p.h[3]=(_Float16)a1[3];
            *(ull*)(slot + zo1) = p.u;
            p.h[0]=(_Float16)a2[0]; p.h[1]=(_Float16)a2[1]; p.h[2]=(_Float16)a2[2]; p.h[3]=(_Float16)a2[3];
            *(ull*)(slot + 8192 + zo0) = p.u;
            p.h[0]=(_Float16)a3[0]; p.h[1]=(_Float16)a3[1]; p.h[2]=(_Float16)a3[2]; p.h[3]=(_Float16)a3[3];
            *(ull*)(slot + 8192 + zo1) = p.u;
            *(f32x4*)(slot + io0) = a4;
            *(f32x4*)(slot + io1) = a5;
        }
    }
}

// ---------------------------------------------------------------------------
// rec phase: grid 8 (one block per 16-row chunk), 512 thr = 8 waves.
// Wave w: units 32w..32w+31; z,r rec-tiles in VGPRs, h rec-tiles in LDS.
// Per step: 48 MFMA/wave; gates in-wave; h(t) -> LDS ping-pong + hseq stream.
// ---------------------------------------------------------------------------
#define XPLOAD(i_, Z0, Z1, R0, R1, I0, I1) do {                                \
    const char* s_ = xpc + (size_t)(i_) * 32768;                               \
    Z0 = *(const ull*)(s_ + zo0);        Z1 = *(const ull*)(s_ + zo1);         \
    R0 = *(const ull*)(s_ + 8192 + zo0); R1 = *(const ull*)(s_ + 8192 + zo1);  \
    I0 = *(const f32x4*)(s_ + io0);      I1 = *(const f32x4*)(s_ + io1);       \
} while (0)

#define REC_BODY(IL, CUR, Z0, Z1, R0, R1, I0, I1, NZ0, NZ1, NR0, NR1, NI0, NI1) do { \
    __syncthreads();                                                           \
    if ((IL) + 1 < SEG) XPLOAD((IL) + 1, NZ0, NZ1, NR0, NR1, NI0, NI1);        \
    const int T_ = t0seg + (IL);                                               \
    if ((IL) > 0) {                                                            \
        uint4v v_ = *(const uint4v*)(AhF + (CUR) * 4096 + tid * 8);            \
        *(uint4v*)(hseqc + (size_t)(T_ - 1) * 8192 + tid * 16) = v_;           \
    }                                                                          \
    f32x4 az0 = {0,0,0,0}, az1 = {0,0,0,0}, ar0 = {0,0,0,0}, ar1 = {0,0,0,0};  \
    f32x4 ah0 = {Bh0,Bh0,Bh0,Bh0}, ah1 = {Bh1,Bh1,Bh1,Bh1};                    \
    _Pragma("unroll")                                                          \
    for (int kt = 0; kt < 8; ++kt) {                                           \
        half8 a  = *(const half8*)(AhF + (CUR) * 4096 + (kt * 64 + lane) * 8); \
        half8 b4 = *(const half8*)(BlF + (w*2+0) * 4096 + (kt * 64 + lane) * 8); \
        half8 b5 = *(const half8*)(BlF + (w*2+1) * 4096 + (kt * 64 + lane) * 8); \
        az0 = MFMA(a, bz0f[kt], az0, 0,0,0); az1 = MFMA(a, bz1f[kt], az1, 0,0,0); \
        ar0 = MFMA(a, br0f[kt], ar0, 0,0,0); ar1 = MFMA(a, br1f[kt], ar1, 0,0,0); \
        ah0 = MFMA(a, b4, ah0, 0,0,0);       ah1 = MFMA(a, b5, ah1, 0,0,0);    \
    }                                                                          \
    union { ull u; _Float16 h[4]; } uz0_, uz1_, ur0_, ur1_;                    \
    uz0_.u = Z0; uz1_.u = Z1; ur0_.u = R0; ur1_.u = R1;                        \
    _Pragma("unroll")                                                          \
    for (int j = 0; j < 4; ++j) {                                              \
        float zp0 = az0[j] + (float)uz0_.h[j];                                 \
        float rp0 = ar0[j] + (float)ur0_.h[j];                                 \
        float z0 = 1.f / (1.f + __expf(-zp0));                                 \
        float r0 = 1.f / (1.f + __expf(-rp0));                                 \
        float pre0 = I0[j] + r0 * ah0[j];                                      \
        float e0 = __expf(2.f * pre0);                                         \
        float th0 = 1.f - 2.f / (e0 + 1.f);                                    \
        float h0 = z0 * hp0[j] + (1.f - z0) * th0; hp0[j] = h0;                \
        AhF[((CUR) ^ 1) * 4096 + ho0 + j * 8] = (_Float16)h0;                  \
        float zp1 = az1[j] + (float)uz1_.h[j];                                 \
        float rp1 = ar1[j] + (float)ur1_.h[j];                                 \
        float z1 = 1.f / (1.f + __expf(-zp1));                                 \
        float r1 = 1.f / (1.f + __expf(-rp1));                                 \
        float pre1 = I1[j] + r1 * ah1[j];                                      \
        float e1 = __expf(2.f * pre1);                                         \
        float th1 = 1.f - 2.f / (e1 + 1.f);                                    \
        float h1 = z1 * hp1[j] + (1.f - z1) * th1; hp1[j] = h1;                \
        AhF[((CUR) ^ 1) * 4096 + ho1 + j * 8] = (_Float16)h1;                  \
        if (isl3 && T_ == TSTEPS - 1) {                                        \
            out[(size_t)(b0row + 4 * q + j) * 256 + u0] = h0;                  \
            out[(size_t)(b0row + 4 * q + j) * 256 + u1] = h1;                  \
        }                                                                      \
    }                                                                          \
} while (0)

__launch_bounds__(512, 2)
__global__ void rec_kernel(const _Float16* __restrict__ Wp, const float* __restrict__ Bp,
                           _Float16* __restrict__ hseq, const char* __restrict__ xp,
                           float* __restrict__ hst, float* __restrict__ out,
                           int l, int t0seg)
{
    __shared__ _Float16 Ah[2][4096];     // 16KB ping-pong h-fragments
    __shared__ _Float16 Bl[16][4096];    // 128KB: 2 LDS h-tiles per wave
    _Float16* AhF = &Ah[0][0];
    _Float16* BlF = &Bl[0][0];

    const int tid = threadIdx.x, lane = tid & 63, w = tid >> 6;
    const int lo16 = lane & 15, q = lane >> 4;
    const int c = blockIdx.x;
    const int b0row = c * 16;
    const bool isl3 = (l == 3);

    half8 bz0f[8], bz1f[8], br0f[8], br1f[8];
    {
        const _Float16* wb = Wp + (size_t)l * WPL;
        const int zt0 = 2*w, zt1 = 2*w + 1, rt0 = 16 + 2*w, rt1 = 17 + 2*w;
        const int it0 = 32 + 2*w, it1 = 33 + 2*w;
#pragma unroll
        for (int kt = 0; kt < 8; ++kt) {
            const size_t o = ((size_t)(8 + kt) * 64 + lane) * 8;   // recurrent half
            bz0f[kt] = *(const half8*)(wb + (size_t)zt0 * TILE_STRIDE + o);
            bz1f[kt] = *(const half8*)(wb + (size_t)zt1 * TILE_STRIDE + o);
            br0f[kt] = *(const half8*)(wb + (size_t)rt0 * TILE_STRIDE + o);
            br1f[kt] = *(const half8*)(wb + (size_t)rt1 * TILE_STRIDE + o);
            *(half8*)(BlF + (w*2+0) * 4096 + (kt*64+lane)*8) = *(const half8*)(wb + (size_t)it0 * TILE_STRIDE + o);
            *(half8*)(BlF + (w*2+1) * 4096 + (kt*64+lane)*8) = *(const half8*)(wb + (size_t)it1 * TILE_STRIDE + o);
        }
    }
    const int u0 = 32 * w + lo16, u1 = u0 + 16;
    const float Bh0 = Bp[l * 1024 + 768 + u0];
    const float Bh1 = Bp[l * 1024 + 768 + u1];

    // xp offsets (match xp_kernel store layout)
    const unsigned zo0 = (unsigned)(u0 * 32 + q * 8), zo1 = (unsigned)(u1 * 32 + q * 8);
    const unsigned io0 = (unsigned)(16384 + u0 * 64 + q * 16);
    const unsigned io1 = (unsigned)(16384 + u1 * 64 + q * 16);
    const char* xpc = xp + (size_t)c * SEG * 32768;
    char* hseqc = (char*)hseq + (size_t)c * TSTEPS * 8192;
    char* hstc  = (char*)hst + (size_t)c * 16384;

    // h fragment offsets for this lane's units (rows 4q..4q+3)
    const int ho0 = (w * 64 + (lo16 >> 3) * 16 + 4 * q) * 8 + (lo16 & 7);
    const int ho1 = (w * 64 + (2 + (lo16 >> 3)) * 16 + 4 * q) * 8 + (lo16 & 7);

    // ---- init h(t0-1): Ah[0] + hprev registers ----
    if (t0seg == 0) {
        uint4v z = {0u, 0u, 0u, 0u};
        *(uint4v*)(AhF + tid * 8) = z;
    } else {
        *(uint4v*)(AhF + tid * 8) =
            *(const uint4v*)(hseqc + (size_t)(t0seg - 1) * 8192 + tid * 16);
    }
    float hp0[4], hp1[4];
    if (t0seg == 0) {
#pragma unroll
        for (int j = 0; j < 4; ++j) { hp0[j] = 0.f; hp1[j] = 0.f; }
    } else {
        f32x4 v0 = *(const f32x4*)(hstc + u0 * 64 + q * 16);
        f32x4 v1 = *(const f32x4*)(hstc + u1 * 64 + q * 16);
#pragma unroll
        for (int j = 0; j < 4; ++j) { hp0[j] = v0[j]; hp1[j] = v1[j]; }
    }

    ull zA0, zA1, rA0, rA1, zB0, zB1, rB0, rB1;
    f32x4 iA0, iA1, iB0, iB1;
    XPLOAD(0, zA0, zA1, rA0, rA1, iA0, iA1);

    for (int i = 0; i < SEG; i += 2) {
        REC_BODY(i,     0, zA0, zA1, rA0, rA1, iA0, iA1,
                           zB0, zB1, rB0, rB1, iB0, iB1);
        REC_BODY(i + 1, 1, zB0, zB1, rB0, rB1, iB0, iB1,
                           zA0, zA1, rA0, rA1, iA0, iA1);
    }

    // ---- epilogue: final h (in Ah[0], SEG even) -> hseq; hprev -> hst ----
    __syncthreads();
    {
        uint4v v = *(const uint4v*)(AhF + tid * 8);
        *(uint4v*)(hseqc + (size_t)(t0seg + SEG - 1) * 8192 + tid * 16) = v;
    }
    *(f32x4*)(hstc + u0 * 64 + q * 16) = (f32x4){hp0[0], hp0[1], hp0[2], hp0[3]};
    *(f32x4*)(hstc + u1 * 64 + q * 16) = (f32x4){hp1[0], hp1[1], hp1[2], hp1[3]};
}

extern "C" void kernel_launch(void* const* d_in, const int* in_sizes, int n_in,
                              void* d_out, int out_size, void* d_ws, size_t ws_size,
                              hipStream_t stream)
{
    const float* x     = (const float*)d_in[0];
    const float* k0    = (const float*)d_in[1];
    const float* rk0   = (const float*)d_in[2];
    const float* b0    = (const float*)d_in[3];
    const float* kern  = (const float*)d_in[4];
    const float* rkern = (const float*)d_in[5];
    const float* bias  = (const float*)d_in[6];
    float* out = (float*)d_out;

    char* ws = (char*)d_ws;
    _Float16* Wp   = (_Float16*)(ws + WP_OFF);
    float*    Bp   = (float*)(ws + BP_OFF);
    float*    hst  = (float*)(ws + HST_OFF);
    _Float16* hseq = (_Float16*)(ws + HSEQ_OFF);
    char*     xpb  = ws + XP_OFF;

    const int total = LAYERS * WPL + LAYERS * 1024;
    repack_kernel<<<(total + 255) / 256, 256, 0, stream>>>(k0, rk0, b0, kern, rkern, bias, Wp, Bp);

    for (int l = 0; l < LAYERS; ++l) {
        for (int s = 0; s < NSEG; ++s) {
            xp_kernel<<<32, 512, 0, stream>>>(x, Wp, Bp, hseq, xpb, l, s * SEG);
            rec_kernel<<<8, 512, 0, stream>>>(Wp, Bp, hseq, xpb, hst, out, l, s * SEG);
        }
    }
}